// Round 1
// baseline (2215.631 us; speedup 1.0000x reference)
//
#include <hip/hip_runtime.h>
#include <math.h>

// Problem constants (from reference setup_inputs)
#define kB 32768
#define kD 2048
#define kH 1024
#define kL 384
#define kP 192
#define kC 10
#define kNP 2
#define kND 2
#define kNCAT 768   // kL + kNP*kP
#define kTAU 0.1f
#define kEPS 1e-5f
#define NPART 128
#define RPP (kB / NPART)   // 256 rows per partial

// GEMM tiling
#define BM 128
#define BN 128
#define BK 16
#define LDT (BM + 4)   // padded LDS leading dim (132): 16B-aligned fragment reads

// ---------------------------------------------------------------------------
// GEMM1: C[m,n] = sum_k A[m,k] * W[n,k]   (both row-major, K-contiguous, "NT")
// ---------------------------------------------------------------------------
__global__ __launch_bounds__(256, 4)
void gemm1_nt(const float* __restrict__ A, const float* __restrict__ W,
              float* __restrict__ Cmat, int M, int N, int K)
{
    __shared__ float As[BK * LDT];
    __shared__ float Bs[BK * LDT];
    const int t  = threadIdx.x;
    const int m0 = blockIdx.y * BM, n0 = blockIdx.x * BN;
    const int r  = t >> 2;              // 0..63
    const int kc = (t & 3) * 4;         // 0,4,8,12
    const int tx = t & 15, ty = t >> 4; // 16x16 thread grid, 8x8 micro-tile

    float acc[8][8];
#pragma unroll
    for (int i = 0; i < 8; ++i)
#pragma unroll
        for (int j = 0; j < 8; ++j) acc[i][j] = 0.f;

    for (int kt = 0; kt < K; kt += BK) {
        const float4 a0 = *(const float4*)&A[(size_t)(m0 + r)      * K + kt + kc];
        const float4 a1 = *(const float4*)&A[(size_t)(m0 + r + 64) * K + kt + kc];
        const float4 b0 = *(const float4*)&W[(size_t)(n0 + r)      * K + kt + kc];
        const float4 b1 = *(const float4*)&W[(size_t)(n0 + r + 64) * K + kt + kc];
        __syncthreads();   // protect previous iteration's LDS reads
        As[(kc + 0) * LDT + r] = a0.x;  As[(kc + 1) * LDT + r] = a0.y;
        As[(kc + 2) * LDT + r] = a0.z;  As[(kc + 3) * LDT + r] = a0.w;
        As[(kc + 0) * LDT + r + 64] = a1.x;  As[(kc + 1) * LDT + r + 64] = a1.y;
        As[(kc + 2) * LDT + r + 64] = a1.z;  As[(kc + 3) * LDT + r + 64] = a1.w;
        Bs[(kc + 0) * LDT + r] = b0.x;  Bs[(kc + 1) * LDT + r] = b0.y;
        Bs[(kc + 2) * LDT + r] = b0.z;  Bs[(kc + 3) * LDT + r] = b0.w;
        Bs[(kc + 0) * LDT + r + 64] = b1.x;  Bs[(kc + 1) * LDT + r + 64] = b1.y;
        Bs[(kc + 2) * LDT + r + 64] = b1.z;  Bs[(kc + 3) * LDT + r + 64] = b1.w;
        __syncthreads();
#pragma unroll
        for (int k = 0; k < BK; ++k) {
            const float4 av0 = *(const float4*)&As[k * LDT + ty * 8];
            const float4 av1 = *(const float4*)&As[k * LDT + ty * 8 + 4];
            const float4 bv0 = *(const float4*)&Bs[k * LDT + tx * 8];
            const float4 bv1 = *(const float4*)&Bs[k * LDT + tx * 8 + 4];
            const float av[8] = {av0.x, av0.y, av0.z, av0.w, av1.x, av1.y, av1.z, av1.w};
            const float bv[8] = {bv0.x, bv0.y, bv0.z, bv0.w, bv1.x, bv1.y, bv1.z, bv1.w};
#pragma unroll
            for (int i = 0; i < 8; ++i)
#pragma unroll
                for (int j = 0; j < 8; ++j)
                    acc[i][j] = fmaf(av[i], bv[j], acc[i][j]);
        }
    }
#pragma unroll
    for (int i = 0; i < 8; ++i) {
        const int row = m0 + ty * 8 + i;
        float4 o0 = {acc[i][0], acc[i][1], acc[i][2], acc[i][3]};
        float4 o1 = {acc[i][4], acc[i][5], acc[i][6], acc[i][7]};
        *(float4*)&Cmat[(size_t)row * N + n0 + tx * 8]     = o0;
        *(float4*)&Cmat[(size_t)row * N + n0 + tx * 8 + 4] = o1;
    }
}

// ---------------------------------------------------------------------------
// GEMM2: A = relu(Z1*scale+shift) applied on load (fused BN+ReLU of layer 1).
// B rows 0..kL-1 come from W_disc, rows kL.. from W1 (both [*,1024] row-major).
// C = Z2cat [B, 768]: cols 0..383 pre-BN disc, cols 384..767 expert pre-act.
// ---------------------------------------------------------------------------
__global__ __launch_bounds__(256, 4)
void gemm2_nt(const float* __restrict__ Z1,
              const float* __restrict__ scale, const float* __restrict__ shift,
              const float* __restrict__ Wd, const float* __restrict__ W1,
              float* __restrict__ Cmat)
{
    const int M = kB, N = kNCAT, K = kH;
    __shared__ float As[BK * LDT];
    __shared__ float Bs[BK * LDT];
    const int t  = threadIdx.x;
    const int m0 = blockIdx.y * BM, n0 = blockIdx.x * BN;
    const int r  = t >> 2;
    const int kc = (t & 3) * 4;
    const int tx = t & 15, ty = t >> 4;

    float acc[8][8];
#pragma unroll
    for (int i = 0; i < 8; ++i)
#pragma unroll
        for (int j = 0; j < 8; ++j) acc[i][j] = 0.f;

    for (int kt = 0; kt < K; kt += BK) {
        float4 a0 = *(const float4*)&Z1[(size_t)(m0 + r)      * K + kt + kc];
        float4 a1 = *(const float4*)&Z1[(size_t)(m0 + r + 64) * K + kt + kc];
        const float4 sc = *(const float4*)&scale[kt + kc];
        const float4 sh = *(const float4*)&shift[kt + kc];
        a0.x = fmaxf(fmaf(a0.x, sc.x, sh.x), 0.f);
        a0.y = fmaxf(fmaf(a0.y, sc.y, sh.y), 0.f);
        a0.z = fmaxf(fmaf(a0.z, sc.z, sh.z), 0.f);
        a0.w = fmaxf(fmaf(a0.w, sc.w, sh.w), 0.f);
        a1.x = fmaxf(fmaf(a1.x, sc.x, sh.x), 0.f);
        a1.y = fmaxf(fmaf(a1.y, sc.y, sh.y), 0.f);
        a1.z = fmaxf(fmaf(a1.z, sc.z, sh.z), 0.f);
        a1.w = fmaxf(fmaf(a1.w, sc.w, sh.w), 0.f);
        const int n_lo = n0 + r, n_hi = n0 + r + 64;
        const float* rowlo = (n_lo < kL) ? (Wd + (size_t)n_lo * K) : (W1 + (size_t)(n_lo - kL) * K);
        const float* rowhi = (n_hi < kL) ? (Wd + (size_t)n_hi * K) : (W1 + (size_t)(n_hi - kL) * K);
        const float4 b0 = *(const float4*)&rowlo[kt + kc];
        const float4 b1 = *(const float4*)&rowhi[kt + kc];
        __syncthreads();
        As[(kc + 0) * LDT + r] = a0.x;  As[(kc + 1) * LDT + r] = a0.y;
        As[(kc + 2) * LDT + r] = a0.z;  As[(kc + 3) * LDT + r] = a0.w;
        As[(kc + 0) * LDT + r + 64] = a1.x;  As[(kc + 1) * LDT + r + 64] = a1.y;
        As[(kc + 2) * LDT + r + 64] = a1.z;  As[(kc + 3) * LDT + r + 64] = a1.w;
        Bs[(kc + 0) * LDT + r] = b0.x;  Bs[(kc + 1) * LDT + r] = b0.y;
        Bs[(kc + 2) * LDT + r] = b0.z;  Bs[(kc + 3) * LDT + r] = b0.w;
        Bs[(kc + 0) * LDT + r + 64] = b1.x;  Bs[(kc + 1) * LDT + r + 64] = b1.y;
        Bs[(kc + 2) * LDT + r + 64] = b1.z;  Bs[(kc + 3) * LDT + r + 64] = b1.w;
        __syncthreads();
#pragma unroll
        for (int k = 0; k < BK; ++k) {
            const float4 av0 = *(const float4*)&As[k * LDT + ty * 8];
            const float4 av1 = *(const float4*)&As[k * LDT + ty * 8 + 4];
            const float4 bv0 = *(const float4*)&Bs[k * LDT + tx * 8];
            const float4 bv1 = *(const float4*)&Bs[k * LDT + tx * 8 + 4];
            const float av[8] = {av0.x, av0.y, av0.z, av0.w, av1.x, av1.y, av1.z, av1.w};
            const float bv[8] = {bv0.x, bv0.y, bv0.z, bv0.w, bv1.x, bv1.y, bv1.z, bv1.w};
#pragma unroll
            for (int i = 0; i < 8; ++i)
#pragma unroll
                for (int j = 0; j < 8; ++j)
                    acc[i][j] = fmaf(av[i], bv[j], acc[i][j]);
        }
    }
#pragma unroll
    for (int i = 0; i < 8; ++i) {
        const int row = m0 + ty * 8 + i;
        float4 o0 = {acc[i][0], acc[i][1], acc[i][2], acc[i][3]};
        float4 o1 = {acc[i][4], acc[i][5], acc[i][6], acc[i][7]};
        *(float4*)&Cmat[(size_t)row * N + n0 + tx * 8]     = o0;
        *(float4*)&Cmat[(size_t)row * N + n0 + tx * 8 + 4] = o1;
    }
}

// ---------------------------------------------------------------------------
// BatchNorm stats, two-stage deterministic column reduction
// ---------------------------------------------------------------------------
__global__ __launch_bounds__(256)
void colstat_partial(const float* __restrict__ Z, int ldz, int ncols,
                     float* __restrict__ psum, float* __restrict__ psumsq)
{
    const int c = blockIdx.x * 256 + threadIdx.x;
    if (c >= ncols) return;
    const float* p = Z + (size_t)blockIdx.y * RPP * ldz + c;
    float s = 0.f, sq = 0.f;
    for (int rr = 0; rr < RPP; ++rr) {
        const float v = p[(size_t)rr * ldz];
        s += v;
        sq = fmaf(v, v, sq);
    }
    psum[(size_t)blockIdx.y * ncols + c]   = s;
    psumsq[(size_t)blockIdx.y * ncols + c] = sq;
}

__global__ __launch_bounds__(256)
void colstat_finalize(const float* __restrict__ psum, const float* __restrict__ psumsq,
                      int ncols, const float* __restrict__ g, const float* __restrict__ be,
                      float* __restrict__ scale, float* __restrict__ shift)
{
    const int c = blockIdx.x * 256 + threadIdx.x;
    if (c >= ncols) return;
    float s = 0.f, sq = 0.f;
    for (int i = 0; i < NPART; ++i) {
        s  += psum[(size_t)i * ncols + c];
        sq += psumsq[(size_t)i * ncols + c];
    }
    const float mu  = s * (1.f / kB);
    const float var = sq * (1.f / kB) - mu * mu;   // biased variance
    const float scl = g[c] * rsqrtf(var + kEPS);
    scale[c] = scl;
    shift[c] = fmaf(-mu, scl, be[c]);
}

// ---------------------------------------------------------------------------
// Tail: per-row BN2+ReLU -> dom, sw, gumbel-softmax routing, selected expert.
// One wave (64 lanes) per row, 4 rows per block.
// ---------------------------------------------------------------------------
__global__ __launch_bounds__(256)
void tail_kernel(const float* __restrict__ Z2,
                 const float* __restrict__ scale2, const float* __restrict__ shift2,
                 const float* __restrict__ W_dfc, const float* __restrict__ b_dfc,
                 const float* __restrict__ W_sw, const float* __restrict__ b_sw,
                 const float* __restrict__ b1, const float* __restrict__ W2,
                 const float* __restrict__ b2, const float* __restrict__ noise,
                 float* __restrict__ out)
{
    __shared__ float sWdfc[kND * kL];
    __shared__ float sWsw[kNP * kL];
    __shared__ float sW2[kNP * kC * kP];
    __shared__ float sb1[kNP * kP];
    __shared__ float sScale[kL];
    __shared__ float sShift[kL];
    const int t = threadIdx.x;
    for (int i = t; i < kND * kL; i += 256) sWdfc[i] = W_dfc[i];
    for (int i = t; i < kNP * kL; i += 256) sWsw[i] = W_sw[i];
    for (int i = t; i < kNP * kC * kP; i += 256) sW2[i] = W2[i];
    for (int i = t; i < kNP * kP; i += 256) sb1[i] = b1[i];
    for (int i = t; i < kL; i += 256) { sScale[i] = scale2[i]; sShift[i] = shift2[i]; }
    __syncthreads();

    const int lane = t & 63;
    const int b = blockIdx.x * 4 + (t >> 6);
    const float* z = Z2 + (size_t)b * kNCAT;

    // dp (fused BN+ReLU) and the four K=384 dot products
    float d0 = 0.f, d1 = 0.f, s0 = 0.f, s1 = 0.f;
#pragma unroll
    for (int j = 0; j < 6; ++j) {
        const int k = lane + j * 64;
        const float dp = fmaxf(fmaf(z[k], sScale[k], sShift[k]), 0.f);
        d0 = fmaf(dp, sWdfc[k],      d0);
        d1 = fmaf(dp, sWdfc[kL + k], d1);
        s0 = fmaf(dp, sWsw[k],       s0);
        s1 = fmaf(dp, sWsw[kL + k],  s1);
    }
#pragma unroll
    for (int off = 32; off; off >>= 1) {
        d0 += __shfl_xor(d0, off);
        d1 += __shfl_xor(d1, off);
        s0 += __shfl_xor(s0, off);
        s1 += __shfl_xor(s1, off);
    }
    d0 += b_dfc[0];
    d1 += b_dfc[1];

    // gumbel-softmax routing (argmax of softmax == argmax of logits; first-index ties)
    const float sw0 = fmaxf(s0 + b_sw[0], 0.f);
    const float sw1 = fmaxf(s1 + b_sw[1], 0.f);
    const float l0 = (sw0 + noise[(size_t)b * 2 + 0]) * (1.f / kTAU);
    const float l1 = (sw1 + noise[(size_t)b * 2 + 1]) * (1.f / kTAU);
    const float mx = fmaxf(l0, l1);
    const float e0 = expf(l0 - mx), e1 = expf(l1 - mx);
    const float inv = 1.f / (e0 + e1);
    const float sgum = e0 * inv + e1 * inv;  // faithful sum(gum) (~1.0)
    const int idx = (l1 > l0) ? 1 : 0;

    // selected expert: h = relu(z_expert + b1[idx]); o = h @ W2[idx].T + b2[idx]
    const float* zh = z + kL + idx * kP;
    const float h0 = fmaxf(zh[lane]       + sb1[idx * kP + lane],       0.f);
    const float h1 = fmaxf(zh[lane + 64]  + sb1[idx * kP + lane + 64],  0.f);
    const float h2 = fmaxf(zh[lane + 128] + sb1[idx * kP + lane + 128], 0.f);

    float* cop  = out;
    float* dom  = out + (size_t)kB * kC;
    float* idxo = dom + (size_t)kB * kND;

#pragma unroll
    for (int c = 0; c < kC; ++c) {
        const float* w = &sW2[(idx * kC + c) * kP];
        float oc = h0 * w[lane] + h1 * w[lane + 64] + h2 * w[lane + 128];
#pragma unroll
        for (int off = 32; off; off >>= 1) oc += __shfl_xor(oc, off);
        if (lane == c) cop[(size_t)b * kC + c] = (oc + b2[idx * kC + c]) * sgum;
    }
    if (lane == 0) {
        dom[(size_t)b * 2 + 0] = d0;
        dom[(size_t)b * 2 + 1] = d1;
        idxo[b] = (float)idx;
    }
}

// ---------------------------------------------------------------------------
extern "C" void kernel_launch(void* const* d_in, const int* in_sizes, int n_in,
                              void* d_out, int out_size, void* d_ws, size_t ws_size,
                              hipStream_t stream)
{
    const float* x       = (const float*)d_in[0];
    const float* W_pre   = (const float*)d_in[1];
    // d_in[2] b_pre: cancels exactly through BatchNorm (mean absorbs it)
    const float* g_pre   = (const float*)d_in[3];
    const float* be_pre  = (const float*)d_in[4];
    const float* W_disc  = (const float*)d_in[5];
    // d_in[6] b_disc: cancels through BatchNorm
    const float* g_disc  = (const float*)d_in[7];
    const float* be_disc = (const float*)d_in[8];
    const float* W_dfc   = (const float*)d_in[9];
    const float* b_dfc   = (const float*)d_in[10];
    const float* W_sw    = (const float*)d_in[11];
    const float* b_sw    = (const float*)d_in[12];
    const float* W1      = (const float*)d_in[13];
    const float* b1      = (const float*)d_in[14];
    const float* W2      = (const float*)d_in[15];
    const float* b2      = (const float*)d_in[16];
    const float* noise   = (const float*)d_in[17];

    float* ws     = (float*)d_ws;
    float* Z1     = ws;                               // [B, H]   = 33.55M floats
    float* Z2     = Z1 + (size_t)kB * kH;             // [B, 768] = 25.17M floats
    float* psum   = Z2 + (size_t)kB * kNCAT;          // [NPART, 1024]
    float* psumsq = psum + (size_t)NPART * kH;        // [NPART, 1024]
    float* scale1 = psumsq + (size_t)NPART * kH;      // [1024]
    float* shift1 = scale1 + kH;                      // [1024]
    float* scale2 = shift1 + kH;                      // [384]
    float* shift2 = scale2 + kL;                      // [384]
    float* out    = (float*)d_out;

    // 1) Z1 = x @ W_pre.T   (bias cancels in BN)
    gemm1_nt<<<dim3(kH / BN, kB / BM), 256, 0, stream>>>(x, W_pre, Z1, kB, kH, kD);
    // 2) BN1 stats -> scale1/shift1
    colstat_partial<<<dim3(kH / 256, NPART), 256, 0, stream>>>(Z1, kH, kH, psum, psumsq);
    colstat_finalize<<<dim3(kH / 256), 256, 0, stream>>>(psum, psumsq, kH, g_pre, be_pre, scale1, shift1);
    // 3) Z2 = relu(BN(Z1)) @ [W_disc; W1].T  (BN+ReLU fused into A-load)
    gemm2_nt<<<dim3(kNCAT / BN, kB / BM), 256, 0, stream>>>(Z1, scale1, shift1, W_disc, W1, Z2);
    // 4) BN2 stats on cols 0..383 -> scale2/shift2
    colstat_partial<<<dim3(2, NPART), 256, 0, stream>>>(Z2, kNCAT, kL, psum, psumsq);
    colstat_finalize<<<dim3(2), 256, 0, stream>>>(psum, psumsq, kL, g_disc, be_disc, scale2, shift2);
    // 5) routing + experts + outputs
    tail_kernel<<<dim3(kB / 4), 256, 0, stream>>>(Z2, scale2, shift2, W_dfc, b_dfc,
                                                  W_sw, b_sw, b1, W2, b2, noise, out);
}

// Round 2
// 756.359 us; speedup vs baseline: 2.9293x; 2.9293x over previous
//
#include <hip/hip_runtime.h>
#include <math.h>

// Problem constants
#define kB 32768
#define kD 2048
#define kH 1024
#define kL 384
#define kP 192
#define kC 10
#define kNP 2
#define kND 2
#define kNCAT 768
#define kTAU 0.1f
#define kEPS 1e-5f
#define NPART 128
#define RPP (kB / NPART)

#define SCALE 64.0f          // operand pre-scale (keeps f16 lo-plane normal)
#define INV_SC2 (1.0f / 4096.0f)  // 1/SCALE^2: GEMM outputs carry 4096x

typedef _Float16 f16x8 __attribute__((ext_vector_type(8)));
typedef _Float16 f16x4 __attribute__((ext_vector_type(4)));
typedef float f32x4 __attribute__((ext_vector_type(4)));

// ---------------------------------------------------------------------------
// async global->LDS, 16B per lane (linear LDS dest: base + lane*16)
// ---------------------------------------------------------------------------
__device__ __forceinline__ void gll16(const unsigned short* g, unsigned short* l)
{
    __builtin_amdgcn_global_load_lds(
        (const __attribute__((address_space(1))) unsigned int*)g,
        (__attribute__((address_space(3))) unsigned int*)l, 16, 0, 0);
}

// ---------------------------------------------------------------------------
// split_pack: fp32 [rows][K] -> packed f16 split planes, pre-swizzled.
// Row layout: K/32 blocks of 128B = 8 chunks(16B): logical chunks 0..3 = hi
// (8 f16 each), 4..7 = lo. Stored chunk index = logical ^ (row & 7).
// Values scaled by 64 (hi = f16(64v), lo = f16(64v - hi)).
// ---------------------------------------------------------------------------
__global__ __launch_bounds__(256)
void split_pack(const float* __restrict__ in, unsigned short* __restrict__ out, int K)
{
    const int row = blockIdx.x;
    const int t = threadIdx.x;
    const int s = row & 7;
    const float* ir = in + (size_t)row * K;
    unsigned short* orow = out + (size_t)row * (K * 2);
    for (int k0 = t * 4; k0 < K; k0 += 1024) {
        const float4 v = *(const float4*)&ir[k0];
        const float a0 = v.x * SCALE, a1 = v.y * SCALE, a2 = v.z * SCALE, a3 = v.w * SCALE;
        const _Float16 h0 = (_Float16)a0, h1 = (_Float16)a1, h2 = (_Float16)a2, h3 = (_Float16)a3;
        const _Float16 l0 = (_Float16)(a0 - (float)h0), l1 = (_Float16)(a1 - (float)h1);
        const _Float16 l2 = (_Float16)(a2 - (float)h2), l3 = (_Float16)(a3 - (float)h3);
        const f16x4 hi = {h0, h1, h2, h3};
        const f16x4 lo = {l0, l1, l2, l3};
        const int kb = k0 >> 5, kk = k0 & 31;
        const int c = kk >> 3, off = kk & 7;
        *(f16x4*)&orow[kb * 64 + ((c ^ s) << 3) + off]       = hi;
        *(f16x4*)&orow[kb * 64 + (((c ^ 4) ^ s) << 3) + off] = lo;
    }
}

// split_bn: same packing, but input = GEMM1 output (4096x scaled), applies
// fused BN+ReLU via precomputed scale/shift (which already embed 1/4096 and
// the x64 output pre-scale). K = 1024 fixed.
__global__ __launch_bounds__(256)
void split_bn(const float* __restrict__ Z, const float* __restrict__ scl,
              const float* __restrict__ shf, unsigned short* __restrict__ out)
{
    const int row = blockIdx.x;
    const int t = threadIdx.x;
    const int s = row & 7;
    const int k0 = t * 4;
    const float4 v = *(const float4*)&Z[(size_t)row * kH + k0];
    const float4 sc = *(const float4*)&scl[k0];
    const float4 sh = *(const float4*)&shf[k0];
    const float a0 = fmaxf(fmaf(v.x, sc.x, sh.x), 0.f);
    const float a1 = fmaxf(fmaf(v.y, sc.y, sh.y), 0.f);
    const float a2 = fmaxf(fmaf(v.z, sc.z, sh.z), 0.f);
    const float a3 = fmaxf(fmaf(v.w, sc.w, sh.w), 0.f);
    const _Float16 h0 = (_Float16)a0, h1 = (_Float16)a1, h2 = (_Float16)a2, h3 = (_Float16)a3;
    const _Float16 l0 = (_Float16)(a0 - (float)h0), l1 = (_Float16)(a1 - (float)h1);
    const _Float16 l2 = (_Float16)(a2 - (float)h2), l3 = (_Float16)(a3 - (float)h3);
    const f16x4 hi = {h0, h1, h2, h3};
    const f16x4 lo = {l0, l1, l2, l3};
    const int kb = k0 >> 5, kk = k0 & 31;
    const int c = kk >> 3, off = kk & 7;
    unsigned short* orow = out + (size_t)row * 2048;
    *(f16x4*)&orow[kb * 64 + ((c ^ s) << 3) + off]       = hi;
    *(f16x4*)&orow[kb * 64 + (((c ^ 4) ^ s) << 3) + off] = lo;
}

// ---------------------------------------------------------------------------
// Split-f16 MFMA GEMM: C[m,n] = sum_k Apk[m,k] * Bpk[n,k]  (both packed NT)
// 128x128 tile, 4 waves (2x2) of 64x64, BK=32, single-buffered LDS,
// global_load_lds staging (LDS linear; swizzle lives in the packed layout).
// 3 MFMA per fragment pair: hi*hi + hi*lo + lo*hi.
// ---------------------------------------------------------------------------
__global__ __launch_bounds__(256, 2)
void gemm_sp(const unsigned short* __restrict__ Apk,
             const unsigned short* __restrict__ Bpk,
             float* __restrict__ C, int N, int nkb)
{
    __shared__ unsigned short As[128 * 64];
    __shared__ unsigned short Bs[128 * 64];
    const int t = threadIdx.x;
    const int lane = t & 63;
    const int w = t >> 6;
    const int wr = w >> 1, wc = w & 1;
    const int lg = lane >> 4, lr = lane & 15, ls = lane & 7;
    const int m0 = blockIdx.y * 128, n0 = blockIdx.x * 128;
    const size_t astride = (size_t)nkb * 64;

    // staging descriptors: LDS chunk Q = (w*4+it)*64 + lane -> row=Q>>3, c=Q&7
    const unsigned short* aG[4];
    const unsigned short* bG[4];
    unsigned short* aL[4];
    unsigned short* bL[4];
#pragma unroll
    for (int it = 0; it < 4; ++it) {
        const int Q = (w * 4 + it) * 64 + lane;
        const int row = Q >> 3, c = Q & 7;
        aG[it] = Apk + (size_t)(m0 + row) * astride + c * 8;
        bG[it] = Bpk + (size_t)(n0 + row) * astride + c * 8;
        aL[it] = &As[(w * 4 + it) * 512];
        bL[it] = &Bs[(w * 4 + it) * 512];
    }

    f32x4 acc[4][4];
#pragma unroll
    for (int mi = 0; mi < 4; ++mi)
#pragma unroll
        for (int ni = 0; ni < 4; ++ni) acc[mi][ni] = (f32x4){0.f, 0.f, 0.f, 0.f};

    const int ca = (lg ^ ls) * 8;   // stored hi-chunk element offset; lo = ca^32

    for (int kb = 0; kb < nkb; ++kb) {
        const size_t ko = (size_t)kb * 64;
#pragma unroll
        for (int it = 0; it < 4; ++it) {
            gll16(aG[it] + ko, aL[it]);
            gll16(bG[it] + ko, bL[it]);
        }
        __syncthreads();   // drains vmcnt: LDS tiles ready

        f16x8 ah[4], al[4], bh[4], bl[4];
#pragma unroll
        for (int mi = 0; mi < 4; ++mi) {
            const int ra = (wr * 64 + mi * 16 + lr) * 64;
            ah[mi] = *(const f16x8*)&As[ra + ca];
            al[mi] = *(const f16x8*)&As[ra + (ca ^ 32)];
            const int rb = (wc * 64 + mi * 16 + lr) * 64;
            bh[mi] = *(const f16x8*)&Bs[rb + ca];
            bl[mi] = *(const f16x8*)&Bs[rb + (ca ^ 32)];
        }
#pragma unroll
        for (int mi = 0; mi < 4; ++mi)
#pragma unroll
            for (int ni = 0; ni < 4; ++ni) {
                acc[mi][ni] = __builtin_amdgcn_mfma_f32_16x16x32_f16(ah[mi], bh[ni], acc[mi][ni], 0, 0, 0);
                acc[mi][ni] = __builtin_amdgcn_mfma_f32_16x16x32_f16(ah[mi], bl[ni], acc[mi][ni], 0, 0, 0);
                acc[mi][ni] = __builtin_amdgcn_mfma_f32_16x16x32_f16(al[mi], bh[ni], acc[mi][ni], 0, 0, 0);
            }
        __syncthreads();   // protect LDS before next overwrite
    }

    // C/D layout (m89-verified): col = lane&15, row = (lane>>4)*4 + j
#pragma unroll
    for (int mi = 0; mi < 4; ++mi)
#pragma unroll
        for (int j = 0; j < 4; ++j) {
            const int row = m0 + wr * 64 + mi * 16 + lg * 4 + j;
            float* cr = C + (size_t)row * N + n0 + wc * 64 + lr;
#pragma unroll
            for (int ni = 0; ni < 4; ++ni) cr[ni * 16] = acc[mi][ni][j];
        }
}

// ---------------------------------------------------------------------------
// BatchNorm stats, two-stage deterministic column reduction
// ---------------------------------------------------------------------------
__global__ __launch_bounds__(256)
void colstat_partial(const float* __restrict__ Z, int ldz, int ncols,
                     float* __restrict__ psum, float* __restrict__ psumsq)
{
    const int c = blockIdx.x * 256 + threadIdx.x;
    if (c >= ncols) return;
    const float* p = Z + (size_t)blockIdx.y * RPP * ldz + c;
    float s = 0.f, sq = 0.f;
    for (int rr = 0; rr < RPP; ++rr) {
        const float v = p[(size_t)rr * ldz];
        s += v;
        sq = fmaf(v, v, sq);
    }
    psum[(size_t)blockIdx.y * ncols + c]   = s;
    psumsq[(size_t)blockIdx.y * ncols + c] = sq;
}

// finalize with exact de-scaling: input Z' = Z/inv_sc; outputs scale/shift s.t.
// Z'*scale + shift == outsc * (BN(Z)*g + be)
__global__ __launch_bounds__(256)
void colstat_finalize(const float* __restrict__ psum, const float* __restrict__ psumsq,
                      int ncols, const float* __restrict__ g, const float* __restrict__ be,
                      float* __restrict__ scale, float* __restrict__ shift,
                      float inv_sc, float outsc)
{
    const int c = blockIdx.x * 256 + threadIdx.x;
    if (c >= ncols) return;
    float s = 0.f, sq = 0.f;
    for (int i = 0; i < NPART; ++i) {
        s  += psum[(size_t)i * ncols + c];
        sq += psumsq[(size_t)i * ncols + c];
    }
    const float mup = s * (1.f / kB);                       // mean of Z'
    const float var = (sq * (1.f / kB) - mup * mup) * inv_sc * inv_sc;  // true var
    const float scl = outsc * g[c] * rsqrtf(var + kEPS) * inv_sc;
    scale[c] = scl;
    shift[c] = fmaf(-mup, scl, outsc * be[c]);
}

// ---------------------------------------------------------------------------
// Tail: per-row BN2+ReLU -> dom, sw, gumbel routing, selected expert.
// Z2 carries a 4096x scale; scale2/shift2 de-scale the disc part exactly;
// expert part de-scaled by 1/4096 explicitly.
// ---------------------------------------------------------------------------
__global__ __launch_bounds__(256)
void tail_kernel(const float* __restrict__ Z2,
                 const float* __restrict__ scale2, const float* __restrict__ shift2,
                 const float* __restrict__ W_dfc, const float* __restrict__ b_dfc,
                 const float* __restrict__ W_sw, const float* __restrict__ b_sw,
                 const float* __restrict__ b1, const float* __restrict__ W2,
                 const float* __restrict__ b2, const float* __restrict__ noise,
                 float* __restrict__ out)
{
    __shared__ float sWdfc[kND * kL];
    __shared__ float sWsw[kNP * kL];
    __shared__ float sW2[kNP * kC * kP];
    __shared__ float sb1[kNP * kP];
    __shared__ float sScale[kL];
    __shared__ float sShift[kL];
    const int t = threadIdx.x;
    for (int i = t; i < kND * kL; i += 256) sWdfc[i] = W_dfc[i];
    for (int i = t; i < kNP * kL; i += 256) sWsw[i] = W_sw[i];
    for (int i = t; i < kNP * kC * kP; i += 256) sW2[i] = W2[i];
    for (int i = t; i < kNP * kP; i += 256) sb1[i] = b1[i];
    for (int i = t; i < kL; i += 256) { sScale[i] = scale2[i]; sShift[i] = shift2[i]; }
    __syncthreads();

    const int lane = t & 63;
    const int b = blockIdx.x * 4 + (t >> 6);
    const float* z = Z2 + (size_t)b * kNCAT;

    float d0 = 0.f, d1 = 0.f, s0 = 0.f, s1 = 0.f;
#pragma unroll
    for (int j = 0; j < 6; ++j) {
        const int k = lane + j * 64;
        const float dp = fmaxf(fmaf(z[k], sScale[k], sShift[k]), 0.f);
        d0 = fmaf(dp, sWdfc[k],      d0);
        d1 = fmaf(dp, sWdfc[kL + k], d1);
        s0 = fmaf(dp, sWsw[k],       s0);
        s1 = fmaf(dp, sWsw[kL + k],  s1);
    }
#pragma unroll
    for (int off = 32; off; off >>= 1) {
        d0 += __shfl_xor(d0, off);
        d1 += __shfl_xor(d1, off);
        s0 += __shfl_xor(s0, off);
        s1 += __shfl_xor(s1, off);
    }
    d0 += b_dfc[0];
    d1 += b_dfc[1];

    const float sw0 = fmaxf(s0 + b_sw[0], 0.f);
    const float sw1 = fmaxf(s1 + b_sw[1], 0.f);
    const float l0 = (sw0 + noise[(size_t)b * 2 + 0]) * (1.f / kTAU);
    const float l1 = (sw1 + noise[(size_t)b * 2 + 1]) * (1.f / kTAU);
    const float mx = fmaxf(l0, l1);
    const float e0 = expf(l0 - mx), e1 = expf(l1 - mx);
    const float inv = 1.f / (e0 + e1);
    const float sgum = e0 * inv + e1 * inv;
    const int idx = (l1 > l0) ? 1 : 0;

    const float* zh = z + kL + idx * kP;
    const float h0 = fmaxf(fmaf(zh[lane],       INV_SC2, sb1[idx * kP + lane]),       0.f);
    const float h1 = fmaxf(fmaf(zh[lane + 64],  INV_SC2, sb1[idx * kP + lane + 64]),  0.f);
    const float h2 = fmaxf(fmaf(zh[lane + 128], INV_SC2, sb1[idx * kP + lane + 128]), 0.f);

    float* cop  = out;
    float* dom  = out + (size_t)kB * kC;
    float* idxo = dom + (size_t)kB * kND;

#pragma unroll
    for (int c = 0; c < kC; ++c) {
        const float* wv = &sW2[(idx * kC + c) * kP];
        float oc = h0 * wv[lane] + h1 * wv[lane + 64] + h2 * wv[lane + 128];
#pragma unroll
        for (int off = 32; off; off >>= 1) oc += __shfl_xor(oc, off);
        if (lane == c) cop[(size_t)b * kC + c] = (oc + b2[idx * kC + c]) * sgum;
    }
    if (lane == 0) {
        dom[(size_t)b * 2 + 0] = d0;
        dom[(size_t)b * 2 + 1] = d1;
        idxo[b] = (float)idx;
    }
}

// ---------------------------------------------------------------------------
extern "C" void kernel_launch(void* const* d_in, const int* in_sizes, int n_in,
                              void* d_out, int out_size, void* d_ws, size_t ws_size,
                              hipStream_t stream)
{
    const float* x       = (const float*)d_in[0];
    const float* W_pre   = (const float*)d_in[1];
    // d_in[2] b_pre: cancels exactly through BatchNorm
    const float* g_pre   = (const float*)d_in[3];
    const float* be_pre  = (const float*)d_in[4];
    const float* W_disc  = (const float*)d_in[5];
    // d_in[6] b_disc: cancels through BatchNorm
    const float* g_disc  = (const float*)d_in[7];
    const float* be_disc = (const float*)d_in[8];
    const float* W_dfc   = (const float*)d_in[9];
    const float* b_dfc   = (const float*)d_in[10];
    const float* W_sw    = (const float*)d_in[11];
    const float* b_sw    = (const float*)d_in[12];
    const float* W1      = (const float*)d_in[13];
    const float* b1      = (const float*)d_in[14];
    const float* W2      = (const float*)d_in[15];
    const float* b2      = (const float*)d_in[16];
    const float* noise   = (const float*)d_in[17];

    // workspace layout (regions reused across phases)
    char* wsb = (char*)d_ws;
    const size_t xs_bytes  = (size_t)kB * (2 * kD) * 2;   // 268.4 MB: xs, later Fs
    const size_t wps_bytes = (size_t)kH * (2 * kD) * 2;   // 8.4 MB: Wps, later Ws2
    const size_t z1_bytes  = (size_t)kB * kH * 4;         // 134.2 MB: Z1', later Z2'
    unsigned short* xs  = (unsigned short*)wsb;
    unsigned short* Fs  = xs;                                   // reuse after gemm1
    unsigned short* Wps = (unsigned short*)(wsb + xs_bytes);
    unsigned short* Ws2 = Wps;                                  // reuse after gemm1
    float* Z1 = (float*)(wsb + xs_bytes + wps_bytes);
    float* Z2 = Z1;                                             // reuse after split_bn
    float* psum   = (float*)(wsb + xs_bytes + wps_bytes + z1_bytes);
    float* psumsq = psum + (size_t)NPART * kH;
    float* scale1 = psumsq + (size_t)NPART * kH;
    float* shift1 = scale1 + kH;
    float* scale2 = shift1 + kH;
    float* shift2 = scale2 + kL;
    float* out    = (float*)d_out;

    // 1) split-pack x (scaled x64) and W_pre (scaled x64)
    split_pack<<<dim3(kB), 256, 0, stream>>>(x, xs, kD);
    split_pack<<<dim3(kH), 256, 0, stream>>>(W_pre, Wps, kD);
    // 2) Z1' = 4096 * (x @ W_pre.T)
    gemm_sp<<<dim3(kH / 128, kB / 128), 256, 0, stream>>>(xs, Wps, Z1, kH, kD / 32);
    // 3) BN1 stats (outsc=64: feature split pre-scale folded in)
    colstat_partial<<<dim3(kH / 256, NPART), 256, 0, stream>>>(Z1, kH, kH, psum, psumsq);
    colstat_finalize<<<dim3(kH / 256), 256, 0, stream>>>(psum, psumsq, kH, g_pre, be_pre,
                                                         scale1, shift1, INV_SC2, SCALE);
    // 4) Fs = pack(64 * relu(BN(Z1)))   [overwrites xs region]
    split_bn<<<dim3(kB), 256, 0, stream>>>(Z1, scale1, shift1, Fs);
    // 5) pack concatenated [W_disc; W1] (x64)  [overwrites Wps region]
    split_pack<<<dim3(kL), 256, 0, stream>>>(W_disc, Ws2, kH);
    split_pack<<<dim3(kNP * kP), 256, 0, stream>>>(W1, Ws2 + (size_t)kL * (2 * kH), kH);
    // 6) Z2' = 4096 * (feature @ [W_disc;W1].T)  [overwrites Z1 region]
    gemm_sp<<<dim3(kNCAT / 128, kB / 128), 256, 0, stream>>>(Fs, Ws2, Z2, kNCAT, kH / 32);
    // 7) BN2 stats on disc cols (outsc=1: tail wants plain BN values)
    colstat_partial<<<dim3(2, NPART), 256, 0, stream>>>(Z2, kNCAT, kL, psum, psumsq);
    colstat_finalize<<<dim3(2), 256, 0, stream>>>(psum, psumsq, kL, g_disc, be_disc,
                                                  scale2, shift2, INV_SC2, 1.0f);
    // 8) routing + experts + outputs
    tail_kernel<<<dim3(kB / 4), 256, 0, stream>>>(Z2, scale2, shift2, W_dfc, b_dfc,
                                                  W_sw, b_sw, b1, W2, b2, noise, out);
}

// Round 3
// 650.473 us; speedup vs baseline: 3.4062x; 1.1628x over previous
//
#include <hip/hip_runtime.h>
#include <math.h>

// Problem constants
#define kB 32768
#define kD 2048
#define kH 1024
#define kL 384
#define kP 192
#define kC 10
#define kNP 2
#define kND 2
#define kNCAT 768
#define kTAU 0.1f
#define kEPS 1e-5f
#define NPART 256                 // stats partials: 2 per 256-row block * 128 blocks
#define SCALE 64.0f               // operand pre-scale (keeps f16 lo-plane normal)
#define INV_SC2 (1.0f / 4096.0f)  // GEMM outputs carry SCALE^2

typedef _Float16 f16x8 __attribute__((ext_vector_type(8)));
typedef _Float16 f16x4 __attribute__((ext_vector_type(4)));
typedef float f32x4 __attribute__((ext_vector_type(4)));

// async global->LDS, 16B per lane (linear LDS dest: base + lane*16)
__device__ __forceinline__ void gll16(const unsigned short* g, unsigned short* l)
{
    __builtin_amdgcn_global_load_lds(
        (const __attribute__((address_space(1))) unsigned int*)g,
        (__attribute__((address_space(3))) unsigned int*)l, 16, 0, 0);
}

// ---------------------------------------------------------------------------
// split_pack (weights only): fp32 [rows][K] -> packed f16 hi/lo planes,
// pre-swizzled. Per 32-k block: 8 chunks of 16B; logical 0..3 hi, 4..7 lo;
// stored chunk = logical ^ (row & 7). Values scaled by 64.
// ---------------------------------------------------------------------------
__global__ __launch_bounds__(256)
void split_pack(const float* __restrict__ in, unsigned short* __restrict__ out, int K)
{
    const int row = blockIdx.x;
    const int t = threadIdx.x;
    const int s = row & 7;
    const float* ir = in + (size_t)row * K;
    unsigned short* orow = out + (size_t)row * (K * 2);
    for (int k0 = t * 4; k0 < K; k0 += 1024) {
        const float4 v = *(const float4*)&ir[k0];
        const float a0 = v.x * SCALE, a1 = v.y * SCALE, a2 = v.z * SCALE, a3 = v.w * SCALE;
        const _Float16 h0 = (_Float16)a0, h1 = (_Float16)a1, h2 = (_Float16)a2, h3 = (_Float16)a3;
        const _Float16 l0 = (_Float16)(a0 - (float)h0), l1 = (_Float16)(a1 - (float)h1);
        const _Float16 l2 = (_Float16)(a2 - (float)h2), l3 = (_Float16)(a3 - (float)h3);
        const f16x4 hi = {h0, h1, h2, h3};
        const f16x4 lo = {l0, l1, l2, l3};
        const int kb = k0 >> 5, kk = k0 & 31;
        const int c = kk >> 3, off = kk & 7;
        *(f16x4*)&orow[kb * 64 + ((c ^ s) << 3) + off]       = hi;
        *(f16x4*)&orow[kb * 64 + (((c ^ 4) ^ s) << 3) + off] = lo;
    }
}

// ---------------------------------------------------------------------------
// Fused split-f16 MFMA GEMM, 256x256 tile, 8 waves (2x4), BK=32.
// A: fp32 source, reg-staged (optional fused BN+ReLU), split hi/lo, ds_write
//    with XOR chunk swizzle. B: pre-packed, global_load_lds (linear).
// Double-buffered LDS, single barrier per K-step; loads issued one full
// MFMA phase ahead of their drain. Epilogue: C store + fused column partial
// sums/sumsq (for BN stats) into psum/psumsq[256][statN].
// ---------------------------------------------------------------------------
template<int KDIM, bool BN>
__global__ __launch_bounds__(512, 1)
void gemm_fused(const float* __restrict__ Afp,
                const unsigned short* __restrict__ Bpk,
                const float* __restrict__ bnsc, const float* __restrict__ bnsh,
                float* __restrict__ C, const int N, const int gridX,
                float* __restrict__ psum, float* __restrict__ psumsq, const int statN)
{
    constexpr int NKB = KDIM / 32;
    __shared__ unsigned short lds[4][256 * 64];   // [0]=A0 [1]=A1 [2]=B0 [3]=B1

    const int t = threadIdx.x;
    const int lane = t & 63;
    const int w = t >> 6;                // 0..7
    const int wr = w >> 2, wc = w & 3;   // 2x4 wave grid; per-wave 128x64
    const int lr = lane & 15, lg = lane >> 4;
    const int ca = (lg ^ (lr & 7)) * 8;  // swizzled hi-chunk elem offset

    // XCD-chunked swizzle (bijective: nwg % 8 == 0)
    const int nwg = gridDim.x;
    const int chunk = nwg >> 3;
    const int bid = blockIdx.x;
    const int logical = (bid & 7) * chunk + (bid >> 3);
    const int bx = logical % gridX, by = logical / gridX;
    const int m0 = by * 256, n0 = bx * 256;

    // A staging: thread -> (row, k-half)
    const int arow = t >> 1;
    const int akh = t & 1;
    const int s7 = arow & 7;
    const int c0 = akh * 2, c1 = akh * 2 + 1;
    const float* aSrc = Afp + (size_t)(m0 + arow) * KDIM + akh * 16;

    // B staging: wave w, issue it: 64 chunks (8 rows) starting at (w*4+it)*64
    const size_t bstride = (size_t)NKB * 64;
    const unsigned short* bG[4];
    int bLoff[4];
#pragma unroll
    for (int it = 0; it < 4; ++it) {
        const int Q = (w * 4 + it) * 64 + lane;
        bG[it] = Bpk + (size_t)(n0 + (Q >> 3)) * bstride + (Q & 7) * 8;
        bLoff[it] = (w * 4 + it) * 512;
    }

    f32x4 acc[8][4];
#pragma unroll
    for (int mi = 0; mi < 8; ++mi)
#pragma unroll
        for (int ni = 0; ni < 4; ++ni) acc[mi][ni] = (f32x4){0.f, 0.f, 0.f, 0.f};

    float4 av[4], scv[4], shv[4];

    auto stage_issue = [&](int kb, int buf) {
        const int kt = kb * 32;
#pragma unroll
        for (int it = 0; it < 4; ++it)
            gll16(bG[it] + (size_t)kb * 64, &lds[2 + buf][bLoff[it]]);
#pragma unroll
        for (int j = 0; j < 4; ++j)
            av[j] = *(const float4*)&aSrc[kt + j * 4];
        if constexpr (BN) {
#pragma unroll
            for (int j = 0; j < 4; ++j) {
                scv[j] = *(const float4*)&bnsc[kt + akh * 16 + j * 4];
                shv[j] = *(const float4*)&bnsh[kt + akh * 16 + j * 4];
            }
        }
    };

    auto stage_write = [&](int buf) {
        float v[16];
#pragma unroll
        for (int j = 0; j < 4; ++j) {
            float4 a = av[j];
            if constexpr (BN) {
                // scale/shift already map Z1' -> 64*relu-input; relu after
                a.x = fmaxf(fmaf(a.x, scv[j].x, shv[j].x), 0.f);
                a.y = fmaxf(fmaf(a.y, scv[j].y, shv[j].y), 0.f);
                a.z = fmaxf(fmaf(a.z, scv[j].z, shv[j].z), 0.f);
                a.w = fmaxf(fmaf(a.w, scv[j].w, shv[j].w), 0.f);
            } else {
                a.x *= SCALE; a.y *= SCALE; a.z *= SCALE; a.w *= SCALE;
            }
            v[j * 4 + 0] = a.x; v[j * 4 + 1] = a.y;
            v[j * 4 + 2] = a.z; v[j * 4 + 3] = a.w;
        }
        f16x8 hi[2], lo[2];
#pragma unroll
        for (int h = 0; h < 2; ++h)
#pragma unroll
            for (int i = 0; i < 8; ++i) {
                const float x = v[h * 8 + i];
                const _Float16 hh = (_Float16)x;
                hi[h][i] = hh;
                lo[h][i] = (_Float16)(x - (float)hh);
            }
        unsigned short* dst = &lds[buf][arow * 64];
        *(f16x8*)&dst[(c0 ^ s7) * 8]       = hi[0];
        *(f16x8*)&dst[(c1 ^ s7) * 8]       = hi[1];
        *(f16x8*)&dst[((c0 ^ 4) ^ s7) * 8] = lo[0];
        *(f16x8*)&dst[((c1 ^ 4) ^ s7) * 8] = lo[1];
    };

    // prologue: stage tile 0 into buffer 0
    stage_issue(0, 0);
    stage_write(0);
    asm volatile("s_waitcnt vmcnt(0) lgkmcnt(0)" ::: "memory");
    __builtin_amdgcn_s_barrier();

    for (int kb = 0; kb < NKB; ++kb) {
        const int cur = kb & 1, nxt = cur ^ 1;
        const bool pf = (kb + 1 < NKB);
        if (pf) stage_issue(kb + 1, nxt);    // loads fly during MFMA phase

        f16x8 bh[4], bl[4];
#pragma unroll
        for (int ni = 0; ni < 4; ++ni) {
            const unsigned short* bb = &lds[2 + cur][(wc * 64 + ni * 16 + lr) * 64];
            bh[ni] = *(const f16x8*)&bb[ca];
            bl[ni] = *(const f16x8*)&bb[ca ^ 32];
        }
#pragma unroll
        for (int mi = 0; mi < 8; ++mi) {
            const unsigned short* ab = &lds[cur][(wr * 128 + mi * 16 + lr) * 64];
            const f16x8 ah = *(const f16x8*)&ab[ca];
            const f16x8 al = *(const f16x8*)&ab[ca ^ 32];
#pragma unroll
            for (int ni = 0; ni < 4; ++ni)
                acc[mi][ni] = __builtin_amdgcn_mfma_f32_16x16x32_f16(ah, bh[ni], acc[mi][ni], 0, 0, 0);
#pragma unroll
            for (int ni = 0; ni < 4; ++ni)
                acc[mi][ni] = __builtin_amdgcn_mfma_f32_16x16x32_f16(ah, bl[ni], acc[mi][ni], 0, 0, 0);
#pragma unroll
            for (int ni = 0; ni < 4; ++ni)
                acc[mi][ni] = __builtin_amdgcn_mfma_f32_16x16x32_f16(al, bh[ni], acc[mi][ni], 0, 0, 0);
        }
        if (pf) stage_write(nxt);
        asm volatile("s_waitcnt vmcnt(0) lgkmcnt(0)" ::: "memory");
        __builtin_amdgcn_s_barrier();
    }

    // C store (scalar; C/D layout: col = lane&15, row = (lane>>4)*4 + j)
#pragma unroll
    for (int mi = 0; mi < 8; ++mi)
#pragma unroll
        for (int j = 0; j < 4; ++j) {
            const int row = m0 + wr * 128 + mi * 16 + lg * 4 + j;
            float* cr = C + (size_t)row * N + n0 + wc * 64 + lr;
#pragma unroll
            for (int ni = 0; ni < 4; ++ni) cr[ni * 16] = acc[mi][ni][j];
        }

    // fused column partial stats over this wave's 128 rows
#pragma unroll
    for (int ni = 0; ni < 4; ++ni) {
        float s = 0.f, sq = 0.f;
#pragma unroll
        for (int mi = 0; mi < 8; ++mi)
#pragma unroll
            for (int j = 0; j < 4; ++j) {
                const float v = acc[mi][ni][j];
                s += v;
                sq = fmaf(v, v, sq);
            }
        s  += __shfl_xor(s, 16);  s  += __shfl_xor(s, 32);
        sq += __shfl_xor(sq, 16); sq += __shfl_xor(sq, 32);
        const int col = n0 + wc * 64 + ni * 16 + lr;
        if (lane < 16 && col < statN) {
            psum[(size_t)(by * 2 + wr) * statN + col]   = s;
            psumsq[(size_t)(by * 2 + wr) * statN + col] = sq;
        }
    }
}

// ---------------------------------------------------------------------------
// finalize: input partials of Z' = Z/inv_sc; output scale/shift s.t.
// Z'*scale + shift == outsc * (BN(Z)*g + be)
// ---------------------------------------------------------------------------
__global__ __launch_bounds__(256)
void colstat_finalize(const float* __restrict__ psum, const float* __restrict__ psumsq,
                      int ncols, const float* __restrict__ g, const float* __restrict__ be,
                      float* __restrict__ scale, float* __restrict__ shift,
                      float inv_sc, float outsc)
{
    const int c = blockIdx.x * 256 + threadIdx.x;
    if (c >= ncols) return;
    float s = 0.f, sq = 0.f;
    for (int i = 0; i < NPART; ++i) {
        s  += psum[(size_t)i * ncols + c];
        sq += psumsq[(size_t)i * ncols + c];
    }
    const float mup = s * (1.f / kB);
    const float var = (sq * (1.f / kB) - mup * mup) * inv_sc * inv_sc;
    const float scl = outsc * g[c] * rsqrtf(var + kEPS) * inv_sc;
    scale[c] = scl;
    shift[c] = fmaf(-mup, scl, outsc * be[c]);
}

// ---------------------------------------------------------------------------
// Tail: per-row BN2+ReLU -> dom, sw, gumbel routing, selected expert.
// Z2 carries a 4096x scale; scale2/shift2 de-scale the disc part exactly;
// expert part de-scaled by 1/4096 explicitly.
// ---------------------------------------------------------------------------
__global__ __launch_bounds__(256)
void tail_kernel(const float* __restrict__ Z2,
                 const float* __restrict__ scale2, const float* __restrict__ shift2,
                 const float* __restrict__ W_dfc, const float* __restrict__ b_dfc,
                 const float* __restrict__ W_sw, const float* __restrict__ b_sw,
                 const float* __restrict__ b1, const float* __restrict__ W2,
                 const float* __restrict__ b2, const float* __restrict__ noise,
                 float* __restrict__ out)
{
    __shared__ float sWdfc[kND * kL];
    __shared__ float sWsw[kNP * kL];
    __shared__ float sW2[kNP * kC * kP];
    __shared__ float sb1[kNP * kP];
    __shared__ float sScale[kL];
    __shared__ float sShift[kL];
    const int t = threadIdx.x;
    for (int i = t; i < kND * kL; i += 256) sWdfc[i] = W_dfc[i];
    for (int i = t; i < kNP * kL; i += 256) sWsw[i] = W_sw[i];
    for (int i = t; i < kNP * kC * kP; i += 256) sW2[i] = W2[i];
    for (int i = t; i < kNP * kP; i += 256) sb1[i] = b1[i];
    for (int i = t; i < kL; i += 256) { sScale[i] = scale2[i]; sShift[i] = shift2[i]; }
    __syncthreads();

    const int lane = t & 63;
    const int b = blockIdx.x * 4 + (t >> 6);
    const float* z = Z2 + (size_t)b * kNCAT;

    float d0 = 0.f, d1 = 0.f, s0 = 0.f, s1 = 0.f;
#pragma unroll
    for (int j = 0; j < 6; ++j) {
        const int k = lane + j * 64;
        const float dp = fmaxf(fmaf(z[k], sScale[k], sShift[k]), 0.f);
        d0 = fmaf(dp, sWdfc[k],      d0);
        d1 = fmaf(dp, sWdfc[kL + k], d1);
        s0 = fmaf(dp, sWsw[k],       s0);
        s1 = fmaf(dp, sWsw[kL + k],  s1);
    }
#pragma unroll
    for (int off = 32; off; off >>= 1) {
        d0 += __shfl_xor(d0, off);
        d1 += __shfl_xor(d1, off);
        s0 += __shfl_xor(s0, off);
        s1 += __shfl_xor(s1, off);
    }
    d0 += b_dfc[0];
    d1 += b_dfc[1];

    const float sw0 = fmaxf(s0 + b_sw[0], 0.f);
    const float sw1 = fmaxf(s1 + b_sw[1], 0.f);
    const float l0 = (sw0 + noise[(size_t)b * 2 + 0]) * (1.f / kTAU);
    const float l1 = (sw1 + noise[(size_t)b * 2 + 1]) * (1.f / kTAU);
    const float mx = fmaxf(l0, l1);
    const float e0 = expf(l0 - mx), e1 = expf(l1 - mx);
    const float inv = 1.f / (e0 + e1);
    const float sgum = e0 * inv + e1 * inv;
    const int idx = (l1 > l0) ? 1 : 0;

    const float* zh = z + kL + idx * kP;
    const float h0 = fmaxf(fmaf(zh[lane],       INV_SC2, sb1[idx * kP + lane]),       0.f);
    const float h1 = fmaxf(fmaf(zh[lane + 64],  INV_SC2, sb1[idx * kP + lane + 64]),  0.f);
    const float h2 = fmaxf(fmaf(zh[lane + 128], INV_SC2, sb1[idx * kP + lane + 128]), 0.f);

    float* cop  = out;
    float* dom  = out + (size_t)kB * kC;
    float* idxo = dom + (size_t)kB * kND;

#pragma unroll
    for (int c = 0; c < kC; ++c) {
        const float* wv = &sW2[(idx * kC + c) * kP];
        float oc = h0 * wv[lane] + h1 * wv[lane + 64] + h2 * wv[lane + 128];
#pragma unroll
        for (int off = 32; off; off >>= 1) oc += __shfl_xor(oc, off);
        if (lane == c) cop[(size_t)b * kC + c] = (oc + b2[idx * kC + c]) * sgum;
    }
    if (lane == 0) {
        dom[(size_t)b * 2 + 0] = d0;
        dom[(size_t)b * 2 + 1] = d1;
        idxo[b] = (float)idx;
    }
}

// ---------------------------------------------------------------------------
extern "C" void kernel_launch(void* const* d_in, const int* in_sizes, int n_in,
                              void* d_out, int out_size, void* d_ws, size_t ws_size,
                              hipStream_t stream)
{
    const float* x       = (const float*)d_in[0];
    const float* W_pre   = (const float*)d_in[1];
    // d_in[2] b_pre: cancels exactly through BatchNorm
    const float* g_pre   = (const float*)d_in[3];
    const float* be_pre  = (const float*)d_in[4];
    const float* W_disc  = (const float*)d_in[5];
    // d_in[6] b_disc: cancels through BatchNorm
    const float* g_disc  = (const float*)d_in[7];
    const float* be_disc = (const float*)d_in[8];
    const float* W_dfc   = (const float*)d_in[9];
    const float* b_dfc   = (const float*)d_in[10];
    const float* W_sw    = (const float*)d_in[11];
    const float* b_sw    = (const float*)d_in[12];
    const float* W1      = (const float*)d_in[13];
    const float* b1      = (const float*)d_in[14];
    const float* W2      = (const float*)d_in[15];
    const float* b2      = (const float*)d_in[16];
    const float* noise   = (const float*)d_in[17];

    // workspace layout
    char* wsb = (char*)d_ws;
    unsigned short* Wps = (unsigned short*)wsb;                       // 1024*4096*2 = 8.39 MB
    unsigned short* Ws2 = (unsigned short*)(wsb + (size_t)1024 * 4096 * 2);  // 768*2048*2 = 3.15 MB
    float* Z1 = (float*)(wsb + (size_t)1024 * 4096 * 2 + (size_t)768 * 2048 * 2);
    float* Z2 = Z1 + (size_t)kB * kH;
    float* psum1  = Z2 + (size_t)kB * kNCAT;
    float* psq1   = psum1 + (size_t)NPART * kH;
    float* psum2  = psq1 + (size_t)NPART * kH;
    float* psq2   = psum2 + (size_t)NPART * kL;
    float* scale1 = psq2 + (size_t)NPART * kL;
    float* shift1 = scale1 + kH;
    float* scale2 = shift1 + kH;
    float* shift2 = scale2 + kL;
    float* out    = (float*)d_out;

    // 1) pack weights (x64): W_pre [1024,2048]; [W_disc; W1] [768,1024]
    split_pack<<<dim3(kH), 256, 0, stream>>>(W_pre, Wps, kD);
    split_pack<<<dim3(kL), 256, 0, stream>>>(W_disc, Ws2, kH);
    split_pack<<<dim3(kNP * kP), 256, 0, stream>>>(W1, Ws2 + (size_t)kL * (2 * kH), kH);
    // 2) Z1' = 4096 * (x @ W_pre.T), fused column partial stats
    gemm_fused<kD, false><<<dim3(4 * 128), 512, 0, stream>>>(
        x, Wps, nullptr, nullptr, Z1, kH, 4, psum1, psq1, kH);
    // 3) BN1 finalize (outsc=64 folds the feature split pre-scale)
    colstat_finalize<<<dim3(kH / 256), 256, 0, stream>>>(psum1, psq1, kH, g_pre, be_pre,
                                                         scale1, shift1, INV_SC2, SCALE);
    // 4) Z2' = 4096 * (relu(BN(Z1)) @ [W_disc;W1].T), BN fused in staging,
    //    fused partial stats for disc cols (<384)
    gemm_fused<kH, true><<<dim3(3 * 128), 512, 0, stream>>>(
        Z1, Ws2, scale1, shift1, Z2, kNCAT, 3, psum2, psq2, kL);
    // 5) BN2 finalize (outsc=1)
    colstat_finalize<<<dim3((kL + 255) / 256), 256, 0, stream>>>(psum2, psq2, kL, g_disc, be_disc,
                                                                 scale2, shift2, INV_SC2, 1.0f);
    // 6) routing + experts + outputs
    tail_kernel<<<dim3(kB / 4), 256, 0, stream>>>(Z2, scale2, shift2, W_dfc, b_dfc,
                                                  W_sw, b_sw, b1, W2, b2, noise, out);
}